// Round 6
// baseline (1141.600 us; speedup 1.0000x reference)
//
#include <hip/hip_runtime.h>

// ---------------------------------------------------------------------------
// MultiHeadAttention (softmax over QUERY axis) — MI355X / gfx950, bf16 MFMA.
// B=4, S=2048, D=1024, H=16, Dk=64. Inputs/outputs fp32.
// attn[i,j] = exp(s_ij)/L_j, L_j = sum_i exp(s_ij)   (column softmax)
//
// ROUND 6: barrier/LDS-free attention.  Transposed score C-layout (i=fr,
// j=fq*4+r) IS the A-operand layout of mfma_f32_16x16x16bf16_1k -> P feeds
// PV straight from registers.  V transposed during its projection GEMM
// (MODE 2 -> Vt[B,H,Dk,S]) so PV B-fragments load directly from global.
// colsum streams Q from global as B-fragments (no LDS, no barriers).
//
// ws (64 MiB): Qb@0 | Kb@16MiB | Vtb@32MiB | Xb@48MiB
// Rl (1/L, 512 KiB fp32) parked in d_out, consumed before final GEMM.
// ---------------------------------------------------------------------------

#define B_   4
#define S_   2048
#define D_   1024
#define H_   16
#define DK_  64
#define BH_  64
#define SCALE_  0.125f
#define EC_     50.0f   // exp clamp: keeps sums finite, no inf*0 NaN

typedef __bf16 bf16x2 __attribute__((ext_vector_type(2)));
typedef __bf16 bf16x4 __attribute__((ext_vector_type(4)));
typedef __bf16 bf16x8 __attribute__((ext_vector_type(8)));
typedef float  f32x4  __attribute__((ext_vector_type(4)));
typedef short  s16x4  __attribute__((ext_vector_type(4)));
typedef unsigned int u32;

#define MFMA32(a,b,c)  __builtin_amdgcn_mfma_f32_16x16x32_bf16((a),(b),(c),0,0,0)
#define MFMA16(a,b,c)  __builtin_amdgcn_mfma_f32_16x16x16bf16_1k((a),(b),(c),0,0,0)

__device__ __forceinline__ bf16x8 ld8(const __bf16* p){ return *(const bf16x8*)p; }
__device__ __forceinline__ s16x4 as_s4(bf16x4 v){ return __builtin_bit_cast(s16x4, v); }

// async global->LDS, 16B per lane; LDS dest = wave-uniform base + lane*16
__device__ __forceinline__ void gll16(const __bf16* g, __bf16* l) {
    __builtin_amdgcn_global_load_lds(
        (const __attribute__((address_space(1))) u32*)g,
        (__attribute__((address_space(3))) u32*)l, 16, 0, 0);
}

// ---------------------------------------------------------------------------
// GEMM  C[m][n] = sum_k A[m][k]*W[k][n] + bias[n]
//   128x128 tile, BK=32, 4 waves (2x2, 64x64 each), 16 MFMA/iter.
//   ABF16=1: A bf16 via global_load_lds; ABF16=0: A fp32, cvt + b128 write.
//   W fp32 [k][n] -> Bs[n][k] bf16, packed k-pair b32 writes, chunk-XOR swizzle.
//   MODE 0: C fp32 [8192][1024]
//   MODE 1: C bf16 scatter [B,H,S,Dk]
//   MODE 2: C bf16 transposed [B,H,Dk,S]  (packed b64 stores along sp)
// ---------------------------------------------------------------------------
template<int ABF16, int MODE>
__global__ __launch_bounds__(256) void gemm128(
    const void* __restrict__ Ap, const float* __restrict__ W,
    const float* __restrict__ bias, void* __restrict__ C)
{
    __shared__ __align__(16) __bf16 As[128*32];
    __shared__ __align__(16) __bf16 Bs[128*32];

    const int t = threadIdx.x, lane = t & 63, w = t >> 6;
    const int wm = w >> 1, wn = w & 1;
    const int fr = lane & 15, fq = lane >> 4;
    const int m0 = blockIdx.y * 128, n0 = blockIdx.x * 128;

    f32x4 acc[4][4];
#pragma unroll
    for (int i = 0; i < 4; ++i)
#pragma unroll
        for (int j = 0; j < 4; ++j) acc[i][j] = (f32x4){0.f,0.f,0.f,0.f};

    for (int kk = 0; kk < D_; kk += 32) {
        __syncthreads();
        if (ABF16) {
            const __bf16* Ab = (const __bf16*)Ap;
#pragma unroll
            for (int p = 0; p < 2; ++p) {
                int c = p*256 + t;
                gll16(&Ab[(size_t)(m0 + (c>>2))*D_ + kk + (c&3)*8],
                      &As[(size_t)(p*256 + (t & ~63))*8]);
            }
        } else {
            const float* Af = (const float*)Ap;
#pragma unroll
            for (int p = 0; p < 2; ++p) {
                int c = p*256 + t;
                int row = c >> 2, kc = (c & 3) * 8;
                const float* ap = &Af[(size_t)(m0 + row)*D_ + kk + kc];
                f32x4 x0 = *(const f32x4*)ap;
                f32x4 x1 = *(const f32x4*)(ap + 4);
                bf16x8 v = { (__bf16)x0[0], (__bf16)x0[1], (__bf16)x0[2], (__bf16)x0[3],
                             (__bf16)x1[0], (__bf16)x1[1], (__bf16)x1[2], (__bf16)x1[3] };
                *(bf16x8*)&As[row*32 + kc] = v;
            }
        }
#pragma unroll
        for (int p = 0; p < 2; ++p) {
            int idx = p*256 + t;
            int nq = idx >> 4, kp = idx & 15;
            const float* wp = &W[(size_t)(kk + 2*kp)*D_ + n0 + nq*4];
            f32x4 w0 = *(const f32x4*)wp;
            f32x4 w1 = *(const f32x4*)(wp + D_);
#pragma unroll
            for (int u = 0; u < 4; ++u) {
                int n = nq*4 + u;
                bf16x2 v = { (__bf16)w0[u], (__bf16)w1[u] };
                *(bf16x2*)&Bs[n*32 + 8*((kp>>2) ^ (n&3)) + 2*(kp&3)] = v;
            }
        }
        __syncthreads();

        bf16x8 af[4], bfr[4];
#pragma unroll
        for (int mt = 0; mt < 4; ++mt)
            af[mt] = ld8(&As[(wm*64 + mt*16 + fr)*32 + fq*8]);
#pragma unroll
        for (int nt = 0; nt < 4; ++nt) {
            int n = wn*64 + nt*16 + fr;
            bfr[nt] = ld8(&Bs[n*32 + 8*(fq ^ (n & 3))]);
        }
#pragma unroll
        for (int mt = 0; mt < 4; ++mt)
#pragma unroll
            for (int nt = 0; nt < 4; ++nt)
                acc[mt][nt] = MFMA32(af[mt], bfr[nt], acc[mt][nt]);
    }

#pragma unroll
    for (int mt = 0; mt < 4; ++mt)
#pragma unroll
        for (int nt = 0; nt < 4; ++nt) {
            int colg = n0 + wn*64 + nt*16 + fr;
            float bv = bias[colg];
            if (MODE == 2) {
                int rowg0 = m0 + wm*64 + mt*16 + fq*4;       // 4 consecutive sp
                int b = rowg0 >> 11, sp = rowg0 & (S_-1);
                int h = colg >> 6, dk = colg & 63;
                bf16x4 v;
#pragma unroll
                for (int r = 0; r < 4; ++r) v[r] = (__bf16)(acc[mt][nt][r] + bv);
                *(bf16x4*)&((__bf16*)C)[(((size_t)(b*H_ + h))*DK_ + dk)*S_ + sp] = v;
            } else {
#pragma unroll
                for (int r = 0; r < 4; ++r) {
                    int rowg = m0 + wm*64 + mt*16 + fq*4 + r;
                    float o = acc[mt][nt][r] + bv;
                    if (MODE == 0) {
                        ((float*)C)[(size_t)rowg*D_ + colg] = o;
                    } else {
                        int b = rowg >> 11, sp = rowg & (S_-1);
                        int h = colg >> 6, dk = colg & 63;
                        ((__bf16*)C)[(((size_t)(b*H_ + h))*S_ + sp)*DK_ + dk] = (__bf16)o;
                    }
                }
            }
        }
}

// ---------------------------------------------------------------------------
// Column-softmax reciprocals: Rl[bh][j] = 1/sum_i exp(clamp(scale*Q_i·K_j)).
//   No LDS, no barriers.  Wave owns 64 j (K-frags in regs), streams Q from
//   global as B-operand fragments (n=i=fr, k=dk=fq*8+..).  Transposed score
//   D[j][i]: lane sums over its i=fr column, shfl-reduce over fr at the end.
// ---------------------------------------------------------------------------
__global__ __launch_bounds__(256) void colsum_rcp(
    const __bf16* __restrict__ Q, const __bf16* __restrict__ K,
    float* __restrict__ Rl)
{
    const int t = threadIdx.x, lane = t & 63, w = t >> 6;
    const int fr = lane & 15, fq = lane >> 4;
    const int bh = blockIdx.y;
    const int jw = blockIdx.x*256 + w*64;
    const __bf16* Qb = Q + (size_t)bh*S_*DK_;
    const __bf16* Kb = K + (size_t)bh*S_*DK_;

    bf16x8 kh[4][2];
#pragma unroll
    for (int jt = 0; jt < 4; ++jt) {
        const __bf16* kr = &Kb[(size_t)(jw + jt*16 + fr)*DK_];
        kh[jt][0] = ld8(kr + fq*8);
        kh[jt][1] = ld8(kr + 32 + fq*8);
    }

    float accl[4][4] = {};
#pragma unroll 2
    for (int i0 = 0; i0 < S_; i0 += 16) {
        const __bf16* qr = &Qb[(size_t)(i0 + fr)*DK_];
        bf16x8 q0 = ld8(qr + fq*8);
        bf16x8 q1 = ld8(qr + 32 + fq*8);
#pragma unroll
        for (int jt = 0; jt < 4; ++jt) {
            f32x4 s = MFMA32(kh[jt][0], q0, ((f32x4){0.f,0.f,0.f,0.f}));
            s = MFMA32(kh[jt][1], q1, s);
#pragma unroll
            for (int r = 0; r < 4; ++r)
                accl[jt][r] += __expf(fminf(s[r]*SCALE_, EC_));
        }
    }
#pragma unroll
    for (int jt = 0; jt < 4; ++jt)
#pragma unroll
        for (int r = 0; r < 4; ++r) {
            accl[jt][r] += __shfl_xor(accl[jt][r], 1, 64);
            accl[jt][r] += __shfl_xor(accl[jt][r], 2, 64);
            accl[jt][r] += __shfl_xor(accl[jt][r], 4, 64);
            accl[jt][r] += __shfl_xor(accl[jt][r], 8, 64);
        }
    if (fr == 0) {
#pragma unroll
        for (int jt = 0; jt < 4; ++jt)
#pragma unroll
            for (int r = 0; r < 4; ++r)
                Rl[(size_t)bh*S_ + jw + jt*16 + fq*4 + r] = 1.0f / accl[jt][r];
    }
}

// ---------------------------------------------------------------------------
// Pass 2: X[i,:] = sum_j (exp(clamp(scale*Q_i·K_j)) * Rl_j) * V[j,:]
//   Zero LDS, zero barriers.  Per 16-j tile:
//     scores transposed (A=K, B=Q -> D[j][i], lane: i=fr, j=fq*4+r)
//     -> exp*Rl -> bf16x4 == A-operand of mfma_f32_16x16x16bf16_1k
//     PV: B-operand = Vt[d][j] (4 consecutive j per lane, b64 global load).
// ---------------------------------------------------------------------------
__global__ __launch_bounds__(256) void attn_pv(
    const __bf16* __restrict__ Q, const __bf16* __restrict__ K,
    const __bf16* __restrict__ Vt, const float* __restrict__ Rl,
    float* __restrict__ X_unused, __bf16* __restrict__ X)
{
    const int t = threadIdx.x, lane = t & 63, w = t >> 6;
    const int fr = lane & 15, fq = lane >> 4;
    const int bh = blockIdx.y;
    const int i0 = blockIdx.x*64 + w*16;
    const __bf16* Qb = Q + (size_t)bh*S_*DK_;
    const __bf16* Kb = K + (size_t)bh*S_*DK_;
    const __bf16* Vb = Vt + (size_t)bh*DK_*S_;
    const float*  Rb = Rl + (size_t)bh*S_;

    bf16x8 aq0 = ld8(&Qb[(size_t)(i0 + fr)*DK_ + fq*8]);
    bf16x8 aq1 = ld8(&Qb[(size_t)(i0 + fr)*DK_ + 32 + fq*8]);

    f32x4 acc[4];
#pragma unroll
    for (int i = 0; i < 4; ++i) acc[i] = (f32x4){0.f,0.f,0.f,0.f};

    for (int jg = 0; jg < S_; jg += 32) {
#pragma unroll
        for (int jt = 0; jt < 2; ++jt) {
            const int jb = jg + jt*16;
            const __bf16* kr = &Kb[(size_t)(jb + fr)*DK_];
            f32x4 s = MFMA32(ld8(kr + fq*8), aq0, ((f32x4){0.f,0.f,0.f,0.f}));
            s = MFMA32(ld8(kr + 32 + fq*8), aq1, s);
            f32x4 rl4 = *(const f32x4*)&Rb[jb + fq*4];
            bf16x4 pv;
#pragma unroll
            for (int r = 0; r < 4; ++r)
                pv[r] = (__bf16)(__expf(fminf(s[r]*SCALE_, EC_)) * rl4[r]);
            s16x4 pa = as_s4(pv);
#pragma unroll
            for (int dt = 0; dt < 4; ++dt) {
                bf16x4 vb = *(const bf16x4*)&Vb[(size_t)(dt*16 + fr)*S_ + jb + fq*4];
                acc[dt] = MFMA16(pa, as_s4(vb), acc[dt]);
            }
        }
    }

    const int b = bh >> 4, h = bh & 15;
#pragma unroll
    for (int dt = 0; dt < 4; ++dt)
#pragma unroll
        for (int r = 0; r < 4; ++r)
            X[((size_t)b*S_ + i0 + fq*4 + r)*D_ + h*DK_ + dt*16 + fr] =
                (__bf16)acc[dt][r];
}

// ---------------------------------------------------------------------------
// Host launcher
// ---------------------------------------------------------------------------
extern "C" void kernel_launch(void* const* d_in, const int* in_sizes, int n_in,
                              void* d_out, int out_size, void* d_ws, size_t ws_size,
                              hipStream_t stream)
{
    const float* query = (const float*)d_in[0];
    const float* key   = (const float*)d_in[1];
    const float* value = (const float*)d_in[2];
    const float* Wq = (const float*)d_in[3];  const float* bq = (const float*)d_in[4];
    const float* Wk = (const float*)d_in[5];  const float* bk = (const float*)d_in[6];
    const float* Wv = (const float*)d_in[7];  const float* bv = (const float*)d_in[8];
    const float* Wo = (const float*)d_in[9];  const float* bo = (const float*)d_in[10];

    char* ws = (char*)d_ws;
    const size_t MiB = 1024 * 1024;
    __bf16* Qb  = (__bf16*)(ws);              // [B,H,S,Dk] 16 MiB
    __bf16* Kb  = (__bf16*)(ws + 16 * MiB);   // [B,H,S,Dk]
    __bf16* Vtb = (__bf16*)(ws + 32 * MiB);   // [B,H,Dk,S] (transposed)
    __bf16* Xb  = (__bf16*)(ws + 48 * MiB);   // [B,S,D]
    float*  Rlb = (float*)d_out;              // 512 KiB, consumed pre-final-GEMM

    dim3 gg(D_/128, (B_*S_)/128);             // (8, 64)
    gemm128<0,1><<<gg, 256, 0, stream>>>(query, Wq, bq, Qb);
    gemm128<0,1><<<gg, 256, 0, stream>>>(key,   Wk, bk, Kb);
    gemm128<0,2><<<gg, 256, 0, stream>>>(value, Wv, bv, Vtb);

    colsum_rcp<<<dim3(S_/256, BH_), 256, 0, stream>>>(Qb, Kb, Rlb);

    attn_pv<<<dim3(S_/64, BH_), 256, 0, stream>>>(Qb, Kb, Vtb, Rlb, nullptr, Xb);

    gemm128<1,0><<<gg, 256, 0, stream>>>(Xb, Wo, bo, d_out);
}